// Round 3
// baseline (445.248 us; speedup 1.0000x reference)
//
#include <hip/hip_runtime.h>
#include <hip/hip_bf16.h>

// SGNHeadLSS fused kernel — round 3.
// Resolved dtype model (evidence r0-r2): ALL inputs float32, output float32.
//  r1 NaN  = f32 weights read as bf16 (garbage exponents -> NaN through LN).
//  r2 2.91 = correct math but output packed as bf16 into an f32 buffer
//            (flat[i] ~ our[2i+1]: same scale, wrong position -> err ~ 2*max|ref|).
// This round: identical compute structure (logic re-audited), f32 output.
//
// Layout:
//  - x3d channel-major: feats[n][c] = x3d[c*NVOX + n]; tiles staged transposed
//    in LDS (sA[c][r], stride 68 -> conflict-free, float4-able over r).
//  - 64-row tiles; masked blocks run MLP-prior (GEMM1+LN+Leaky, GEMM2) first.
//  - ssc_logit out[k*NVOX + n]; sem_logit out[20*NVOX + u*20 + k].

#define NVOX 262144
#define NU   65536
#define NM   196608
#define CIN  128
#define CHALF 64
#define NCLS 20
#define TR   64
#define STR  68
#define NBLK_M (NM / TR) // 3072
#define NBLK_U (NU / TR) // 1024

__global__ __launch_bounds__(256, 3)
void sgn_fused(const float* __restrict__ x3d,
               const float* __restrict__ w1,   const float* __restrict__ b1,
               const float* __restrict__ lng,  const float* __restrict__ lnb,
               const float* __restrict__ w2,   const float* __restrict__ bb2,
               const float* __restrict__ sdbw, const float* __restrict__ sdbb,
               const float* __restrict__ sscw, const float* __restrict__ sscb,
               const float* __restrict__ auxw, const float* __restrict__ auxb,
               const int* __restrict__ uidx,   const int* __restrict__ midx,
               float* __restrict__ out)
{
    __shared__ float sA[CIN * STR];   // feats^T, later prior^T   [c][r]
    __shared__ float sB[CHALF * STR]; // h^T, later d^T           [j][r]
    __shared__ int   sN[TR];

    const int tid = threadIdx.x;
    const bool masked = (blockIdx.x < NBLK_M);
    const int p0 = (masked ? (int)blockIdx.x : ((int)blockIdx.x - NBLK_M)) * TR;
    const int* __restrict__ idx = masked ? midx : uidx;

    const int r   = tid & 63;
    const int n_r = idx[p0 + r];
    if (tid < TR) sN[tid] = n_r;

    // ---- stage feats^T: sA[c][r] ----
    {
        const int cb = (tid >> 6) * 32;
        #pragma unroll 4
        for (int cc = 0; cc < 32; ++cc) {
            const int c = cb + cc;
            sA[c * STR + r] = x3d[(size_t)c * NVOX + n_r];
        }
    }
    __syncthreads();

    const int rg = tid >> 4;
    const int r0 = (rg * 4) & 63;
    const int jg = tid & 15;

    if (masked) {
        // ---- GEMM1: feats @ w1 + b1 -> LN -> Leaky -> sB = h^T ----
        {
            const int j0 = jg * 4;
            float acc[4][4];
            {
                const float4 bv = *(const float4*)&b1[j0];
                #pragma unroll
                for (int i=0;i<4;++i){acc[i][0]=bv.x;acc[i][1]=bv.y;acc[i][2]=bv.z;acc[i][3]=bv.w;}
            }
            #pragma unroll 4
            for (int c = 0; c < CIN; ++c) {
                const float4 f = *(const float4*)&sA[c * STR + r0];
                const float4 w = *(const float4*)&w1[c * CHALF + j0];
                const float fv[4] = {f.x, f.y, f.z, f.w};
                const float wv[4] = {w.x, w.y, w.z, w.w};
                #pragma unroll
                for (int i=0;i<4;++i)
                    #pragma unroll
                    for (int j=0;j<4;++j) acc[i][j] += fv[i]*wv[j];
            }
            float s1[4], s2[4];
            #pragma unroll
            for (int i=0;i<4;++i){
                s1[i]=acc[i][0]+acc[i][1]+acc[i][2]+acc[i][3];
                s2[i]=acc[i][0]*acc[i][0]+acc[i][1]*acc[i][1]
                     +acc[i][2]*acc[i][2]+acc[i][3]*acc[i][3];
            }
            #pragma unroll
            for (int m=1;m<=8;m<<=1){
                #pragma unroll
                for (int i=0;i<4;++i){
                    s1[i]+=__shfl_xor(s1[i],m,64);
                    s2[i]+=__shfl_xor(s2[i],m,64);
                }
            }
            const float4 gv = *(const float4*)&lng[j0];
            const float4 ev = *(const float4*)&lnb[j0];
            const float g[4]={gv.x,gv.y,gv.z,gv.w}, e[4]={ev.x,ev.y,ev.z,ev.w};
            #pragma unroll
            for (int i=0;i<4;++i){
                const float mu  = s1[i]*(1.f/64.f);
                const float var = s2[i]*(1.f/64.f) - mu*mu;
                const float rs  = rsqrtf(var + 1e-5f);
                #pragma unroll
                for (int j=0;j<4;++j){
                    float h = (acc[i][j]-mu)*rs*g[j] + e[j];
                    acc[i][j] = h > 0.f ? h : 0.01f*h;
                }
            }
            #pragma unroll
            for (int j=0;j<4;++j)
                *(float4*)&sB[(j0+j)*STR + r0] =
                    make_float4(acc[0][j],acc[1][j],acc[2][j],acc[3][j]);
        }
        __syncthreads();

        // ---- GEMM2: h @ w2 + b2 -> sA = prior^T ----
        {
            const int q0 = jg * 8;
            float acc[4][8];
            {
                const float4 b0 = *(const float4*)&bb2[q0];
                const float4 b4 = *(const float4*)&bb2[q0+4];
                const float bv[8]={b0.x,b0.y,b0.z,b0.w,b4.x,b4.y,b4.z,b4.w};
                #pragma unroll
                for (int i=0;i<4;++i)
                    #pragma unroll
                    for (int j=0;j<8;++j) acc[i][j]=bv[j];
            }
            #pragma unroll 4
            for (int k=0;k<CHALF;++k){
                const float4 f = *(const float4*)&sB[k*STR + r0];
                const float4 wa = *(const float4*)&w2[k*CIN + q0];
                const float4 wb = *(const float4*)&w2[k*CIN + q0 + 4];
                const float fv[4]={f.x,f.y,f.z,f.w};
                const float wv[8]={wa.x,wa.y,wa.z,wa.w,wb.x,wb.y,wb.z,wb.w};
                #pragma unroll
                for (int i=0;i<4;++i)
                    #pragma unroll
                    for (int j=0;j<8;++j) acc[i][j] += fv[i]*wv[j];
            }
            #pragma unroll
            for (int j=0;j<8;++j)
                *(float4*)&sA[(q0+j)*STR + r0] =
                    make_float4(acc[0][j],acc[1][j],acc[2][j],acc[3][j]);
        }
        __syncthreads();
    }

    // ---- SDB: d = leaky(row @ sdb_w + sdb_b) -> sB = d^T ----
    {
        const int j0 = jg * 4;
        float acc[4][4];
        {
            const float4 bv = *(const float4*)&sdbb[j0];
            #pragma unroll
            for (int i=0;i<4;++i){acc[i][0]=bv.x;acc[i][1]=bv.y;acc[i][2]=bv.z;acc[i][3]=bv.w;}
        }
        #pragma unroll 4
        for (int c=0;c<CIN;++c){
            const float4 f = *(const float4*)&sA[c*STR + r0];
            const float4 w = *(const float4*)&sdbw[c*CHALF + j0];
            const float fv[4]={f.x,f.y,f.z,f.w};
            const float wv[4]={w.x,w.y,w.z,w.w};
            #pragma unroll
            for (int i=0;i<4;++i)
                #pragma unroll
                for (int j=0;j<4;++j) acc[i][j] += fv[i]*wv[j];
        }
        #pragma unroll
        for (int i=0;i<4;++i)
            #pragma unroll
            for (int j=0;j<4;++j){
                const float v = acc[i][j];
                acc[i][j] = v > 0.f ? v : 0.01f*v;
            }
        #pragma unroll
        for (int j=0;j<4;++j)
            *(float4*)&sB[(j0+j)*STR + r0] =
                make_float4(acc[0][j],acc[1][j],acc[2][j],acc[3][j]);
    }
    __syncthreads();

    // ---- SSC head -> out[k*NVOX + n] ----
    {
        const int kg = tid >> 6;  // 0..3, 5 classes each
        float a[5];
        #pragma unroll
        for (int t=0;t<5;++t) a[t] = sscb[kg*5+t];
        for (int c=0;c<CHALF;++c){
            const float dv = sB[c*STR + r];
            #pragma unroll
            for (int t=0;t<5;++t) a[t] += dv * sscw[c*NCLS + kg*5 + t];
        }
        const int n = sN[r];
        #pragma unroll
        for (int t=0;t<5;++t)
            out[(size_t)(kg*5+t)*NVOX + n] = a[t];
    }

    // ---- AUX head (unmasked only) -> out[20*NVOX + u*20 + k] ----
    if (!masked) {
        const int kg = tid >> 6;
        float a[5];
        #pragma unroll
        for (int t=0;t<5;++t) a[t] = auxb[kg*5+t];
        for (int c=0;c<CIN;++c){
            const float fv = sA[c*STR + r];
            #pragma unroll
            for (int t=0;t<5;++t) a[t] += fv * auxw[c*NCLS + kg*5 + t];
        }
        const int u = p0 + r;
        #pragma unroll
        for (int t=0;t<5;++t)
            out[(size_t)NCLS*NVOX + (size_t)u*NCLS + kg*5 + t] = a[t];
    }
}

extern "C" void kernel_launch(void* const* d_in, const int* in_sizes, int n_in,
                              void* d_out, int out_size, void* d_ws, size_t ws_size,
                              hipStream_t stream) {
    const float* x3d  = (const float*)d_in[0];
    const float* w1   = (const float*)d_in[1];
    const float* b1   = (const float*)d_in[2];
    const float* lng  = (const float*)d_in[3];
    const float* lnb  = (const float*)d_in[4];
    const float* w2   = (const float*)d_in[5];
    const float* bb2  = (const float*)d_in[6];
    const float* sdbw = (const float*)d_in[7];
    const float* sdbb = (const float*)d_in[8];
    const float* sscw = (const float*)d_in[9];
    const float* sscb = (const float*)d_in[10];
    const float* auxw = (const float*)d_in[11];
    const float* auxb = (const float*)d_in[12];
    const int*   uidx = (const int*)d_in[13];
    const int*   midx = (const int*)d_in[14];
    float* out = (float*)d_out;

    dim3 grid(NBLK_M + NBLK_U), block(256);
    hipLaunchKernelGGL(sgn_fused, grid, block, 0, stream,
                       x3d, w1, b1, lng, lnb, w2, bb2, sdbw, sdbb,
                       sscw, sscb, auxw, auxb, uidx, midx, out);
}

// Round 4
// 311.294 us; speedup vs baseline: 1.4303x; 1.4303x over previous
//
#include <hip/hip_runtime.h>
#include <hip/hip_bf16.h>

// SGNHeadLSS — round 4: MFMA bf16 rewrite (f32 accumulate).
// r3 post-mortem: VALU-issue-bound (VALUBusy 37%, occ 33%, HBM 8.7%), f32 FMA
// volume is the cost. Move all GEMMs to v_mfma_f32_16x16x32_bf16.
//  - Gather writes LDS tile directly in A-frag row-major [r][k] bf16
//    (lane owns one row x 32 consecutive k -> b128 writes, no transpose).
//  - Weights pre-transposed+bf16-cast once per call into d_ws as W^T[n][k]
//    (B-frag = 16B row reads, B^T-row-major idiom).
//  - Waves split M (16 rows each): after one __syncthreads all phases are
//    wave-local; intra-wave LDS RAW guarded by s_waitcnt lgkmcnt(0).
// Fragment layouts (HW-verified per guide): A[m=lane&15][k=(lane>>4)*8+j],
// B[k=(lane>>4)*8+j][n=lane&15], C col=lane&15 row=(lane>>4)*4+reg.

#define NVOX 262144
#define NU   65536
#define NM   196608
#define CIN  128
#define CHALF 64
#define NCLS 20
#define TR   64
#define NBLK_M (NM / TR) // 3072
#define NBLK_U (NU / TR) // 1024

#define SXS 136   // sX row stride in bf16 (272B, 16B-aligned)
#define SHS 72    // sH row stride in bf16 (144B, 16B-aligned)

// ws layout (u16 units)
#define W1T_OFF  0       // [64][128]   w1^T
#define W2T_OFF  8192    // [128][64]   w2^T
#define SDBT_OFF 16384   // [64][128]   sdb_w^T
#define SSCT_OFF 24576   // [32][64]    ssc_w^T (rows 20..31 zero)
#define AUXT_OFF 26624   // [32][128]   aux_w^T (rows 20..31 zero)
#define WS_TOT   30720   // 61440 bytes

typedef unsigned short u16;
typedef short    bf16x8 __attribute__((ext_vector_type(8)));
typedef float    f32x4  __attribute__((ext_vector_type(4)));

__device__ __forceinline__ u16 f2b(float f) {
    __hip_bfloat16 h = __float2bfloat16(f);
    return *(u16*)&h;
}
__device__ __forceinline__ void wave_sync() {
    // order + drain LDS ops so same-wave cross-lane LDS reuse is safe
    __asm__ volatile("s_waitcnt lgkmcnt(0)" ::: "memory");
}

__global__ void prep_weights(const float* __restrict__ w1,  const float* __restrict__ w2,
                             const float* __restrict__ sdbw,const float* __restrict__ sscw,
                             const float* __restrict__ auxw,u16* __restrict__ ws) {
    int i = blockIdx.x * blockDim.x + threadIdx.x;
    const int stride = gridDim.x * blockDim.x;
    for (; i < WS_TOT; i += stride) {
        float v;
        if (i < W2T_OFF)        { int n = i >> 7, k = i & 127;              v = w1[k*CHALF + n]; }
        else if (i < SDBT_OFF)  { int j = i - W2T_OFF;  int n = j >> 6, k = j & 63;
                                  v = w2[k*CIN + n]; }
        else if (i < SSCT_OFF)  { int j = i - SDBT_OFF; int n = j >> 7, k = j & 127;
                                  v = sdbw[k*CHALF + n]; }
        else if (i < AUXT_OFF)  { int j = i - SSCT_OFF; int n = j >> 6, k = j & 63;
                                  v = (n < NCLS) ? sscw[k*NCLS + n] : 0.f; }
        else                    { int j = i - AUXT_OFF; int n = j >> 7, k = j & 127;
                                  v = (n < NCLS) ? auxw[k*NCLS + n] : 0.f; }
        ws[i] = f2b(v);
    }
}

__global__ __launch_bounds__(256, 4)
void sgn_mfma(const float* __restrict__ x3d,
              const float* __restrict__ b1,   const float* __restrict__ lng,
              const float* __restrict__ lnb,  const float* __restrict__ bb2,
              const float* __restrict__ sdbb, const float* __restrict__ sscb,
              const float* __restrict__ auxb,
              const int* __restrict__ uidx,   const int* __restrict__ midx,
              const u16* __restrict__ wt,     float* __restrict__ out)
{
    __shared__ __align__(16) u16 sX[TR * SXS];  // feats, later prior   [r][k]
    __shared__ __align__(16) u16 sH[TR * SHS];  // h, later d           [r][k]
    __shared__ int sN[TR];

    const int tid = threadIdx.x;
    const bool masked = (blockIdx.x < NBLK_M);
    const int p0 = (masked ? (int)blockIdx.x : ((int)blockIdx.x - NBLK_M)) * TR;
    const int* __restrict__ idx = masked ? midx : uidx;

    const int r   = tid & 63;
    const int n_r = idx[p0 + r];
    if (tid < TR) sN[tid] = n_r;

    // ---- gather x3d -> sX[r][c] bf16 (lane owns row r, 32 consecutive c) ----
    {
        const int cb = (tid >> 6) * 32;
        #pragma unroll
        for (int ch = 0; ch < 4; ++ch) {
            const int c0 = cb + ch * 8;
            float v[8];
            #pragma unroll
            for (int j = 0; j < 8; ++j) v[j] = x3d[(size_t)(c0 + j) * NVOX + n_r];
            bf16x8 pk;
            #pragma unroll
            for (int j = 0; j < 8; ++j) ((u16*)&pk)[j] = f2b(v[j]);
            *(bf16x8*)&sX[r * SXS + c0] = pk;
        }
    }
    __syncthreads();

    const int m0   = (tid >> 6) * 16;  // wave's 16-row slice
    const int lane = tid & 63;
    const int q    = lane >> 4;        // quad
    const int n15  = lane & 15;
    const int kq   = q * 8;            // intra-chunk k offset for A/B frags

    if (masked) {
        // ---- GEMM1: feats[64x128] @ w1[128x64] -> LN -> leaky -> sH ----
        f32x4 acc[4];
        #pragma unroll
        for (int nt = 0; nt < 4; ++nt) {
            const float b = b1[nt*16 + n15];
            acc[nt] = (f32x4){b, b, b, b};
        }
        #pragma unroll
        for (int kc = 0; kc < 4; ++kc) {
            const int k0 = kc * 32;
            const bf16x8 a = *(const bf16x8*)&sX[(m0 + n15) * SXS + k0 + kq];
            #pragma unroll
            for (int nt = 0; nt < 4; ++nt) {
                const bf16x8 b = *(const bf16x8*)&wt[W1T_OFF + (nt*16 + n15)*CIN + k0 + kq];
                acc[nt] = __builtin_amdgcn_mfma_f32_16x16x32_bf16(a, b, acc[nt], 0, 0, 0);
            }
        }
        {
            float gv[4], ev[4];
            #pragma unroll
            for (int nt = 0; nt < 4; ++nt) { gv[nt] = lng[nt*16 + n15]; ev[nt] = lnb[nt*16 + n15]; }
            #pragma unroll
            for (int reg = 0; reg < 4; ++reg) {
                float s1 = acc[0][reg] + acc[1][reg] + acc[2][reg] + acc[3][reg];
                float s2 = acc[0][reg]*acc[0][reg] + acc[1][reg]*acc[1][reg]
                         + acc[2][reg]*acc[2][reg] + acc[3][reg]*acc[3][reg];
                #pragma unroll
                for (int m = 1; m <= 8; m <<= 1) {
                    s1 += __shfl_xor(s1, m, 64);
                    s2 += __shfl_xor(s2, m, 64);
                }
                const float mu  = s1 * (1.f/64.f);
                const float var = s2 * (1.f/64.f) - mu*mu;
                const float rs  = rsqrtf(var + 1e-5f);
                #pragma unroll
                for (int nt = 0; nt < 4; ++nt) {
                    float h = (acc[nt][reg] - mu) * rs * gv[nt] + ev[nt];
                    h = h > 0.f ? h : 0.01f*h;
                    sH[(m0 + q*4 + reg) * SHS + nt*16 + n15] = f2b(h);
                }
            }
        }
        wave_sync();

        // ---- GEMM2: h[64x64] @ w2[64x128] -> prior -> sX ----
        f32x4 acc2[8];
        #pragma unroll
        for (int nt = 0; nt < 8; ++nt) {
            const float b = bb2[nt*16 + n15];
            acc2[nt] = (f32x4){b, b, b, b};
        }
        #pragma unroll
        for (int kc = 0; kc < 2; ++kc) {
            const int k0 = kc * 32;
            const bf16x8 a = *(const bf16x8*)&sH[(m0 + n15) * SHS + k0 + kq];
            #pragma unroll
            for (int nt = 0; nt < 8; ++nt) {
                const bf16x8 b = *(const bf16x8*)&wt[W2T_OFF + (nt*16 + n15)*CHALF + k0 + kq];
                acc2[nt] = __builtin_amdgcn_mfma_f32_16x16x32_bf16(a, b, acc2[nt], 0, 0, 0);
            }
        }
        #pragma unroll
        for (int reg = 0; reg < 4; ++reg)
            #pragma unroll
            for (int nt = 0; nt < 8; ++nt)
                sX[(m0 + q*4 + reg) * SXS + nt*16 + n15] = f2b(acc2[nt][reg]);
        wave_sync();
    }

    // ---- SDB: row[64x128] @ sdb_w[128x64] -> leaky -> sH (= d) ----
    {
        f32x4 accd[4];
        #pragma unroll
        for (int nt = 0; nt < 4; ++nt) {
            const float b = sdbb[nt*16 + n15];
            accd[nt] = (f32x4){b, b, b, b};
        }
        #pragma unroll
        for (int kc = 0; kc < 4; ++kc) {
            const int k0 = kc * 32;
            const bf16x8 a = *(const bf16x8*)&sX[(m0 + n15) * SXS + k0 + kq];
            #pragma unroll
            for (int nt = 0; nt < 4; ++nt) {
                const bf16x8 b = *(const bf16x8*)&wt[SDBT_OFF + (nt*16 + n15)*CIN + k0 + kq];
                accd[nt] = __builtin_amdgcn_mfma_f32_16x16x32_bf16(a, b, accd[nt], 0, 0, 0);
            }
        }
        #pragma unroll
        for (int reg = 0; reg < 4; ++reg)
            #pragma unroll
            for (int nt = 0; nt < 4; ++nt) {
                float v = accd[nt][reg];
                v = v > 0.f ? v : 0.01f*v;
                sH[(m0 + q*4 + reg) * SHS + nt*16 + n15] = f2b(v);
            }
        wave_sync();
    }

    // ---- SSC: d[64x64] @ ssc_w[64x20] -> out[k*NVOX + n] ----
    {
        f32x4 accs[2];
        #pragma unroll
        for (int nt = 0; nt < 2; ++nt) {
            const int col = nt*16 + n15;
            const float b = (col < NCLS) ? sscb[col] : 0.f;
            accs[nt] = (f32x4){b, b, b, b};
        }
        #pragma unroll
        for (int kc = 0; kc < 2; ++kc) {
            const int k0 = kc * 32;
            const bf16x8 a = *(const bf16x8*)&sH[(m0 + n15) * SHS + k0 + kq];
            #pragma unroll
            for (int nt = 0; nt < 2; ++nt) {
                const bf16x8 b = *(const bf16x8*)&wt[SSCT_OFF + (nt*16 + n15)*CHALF + k0 + kq];
                accs[nt] = __builtin_amdgcn_mfma_f32_16x16x32_bf16(a, b, accs[nt], 0, 0, 0);
            }
        }
        int ng[4];
        #pragma unroll
        for (int reg = 0; reg < 4; ++reg) ng[reg] = sN[m0 + q*4 + reg];
        #pragma unroll
        for (int reg = 0; reg < 4; ++reg)
            out[(size_t)n15 * NVOX + ng[reg]] = accs[0][reg];
        if (n15 < 4) {
            #pragma unroll
            for (int reg = 0; reg < 4; ++reg)
                out[(size_t)(16 + n15) * NVOX + ng[reg]] = accs[1][reg];
        }
    }

    // ---- AUX (unmasked): feats[64x128] @ aux_w[128x20] -> out[20*NVOX + u*20 + k] ----
    if (!masked) {
        f32x4 acca[2];
        #pragma unroll
        for (int nt = 0; nt < 2; ++nt) {
            const int col = nt*16 + n15;
            const float b = (col < NCLS) ? auxb[col] : 0.f;
            acca[nt] = (f32x4){b, b, b, b};
        }
        #pragma unroll
        for (int kc = 0; kc < 4; ++kc) {
            const int k0 = kc * 32;
            const bf16x8 a = *(const bf16x8*)&sX[(m0 + n15) * SXS + k0 + kq];
            #pragma unroll
            for (int nt = 0; nt < 2; ++nt) {
                const bf16x8 b = *(const bf16x8*)&wt[AUXT_OFF + (nt*16 + n15)*CIN + k0 + kq];
                acca[nt] = __builtin_amdgcn_mfma_f32_16x16x32_bf16(a, b, acca[nt], 0, 0, 0);
            }
        }
        const size_t base = (size_t)NCLS * NVOX;
        #pragma unroll
        for (int reg = 0; reg < 4; ++reg) {
            const int u = p0 + m0 + q*4 + reg;
            out[base + (size_t)u * NCLS + n15] = acca[0][reg];
            if (n15 < 4)
                out[base + (size_t)u * NCLS + 16 + n15] = acca[1][reg];
        }
    }
}

extern "C" void kernel_launch(void* const* d_in, const int* in_sizes, int n_in,
                              void* d_out, int out_size, void* d_ws, size_t ws_size,
                              hipStream_t stream) {
    const float* x3d  = (const float*)d_in[0];
    const float* w1   = (const float*)d_in[1];
    const float* b1   = (const float*)d_in[2];
    const float* lng  = (const float*)d_in[3];
    const float* lnb  = (const float*)d_in[4];
    const float* w2   = (const float*)d_in[5];
    const float* bb2  = (const float*)d_in[6];
    const float* sdbw = (const float*)d_in[7];
    const float* sdbb = (const float*)d_in[8];
    const float* sscw = (const float*)d_in[9];
    const float* sscb = (const float*)d_in[10];
    const float* auxw = (const float*)d_in[11];
    const float* auxb = (const float*)d_in[12];
    const int*   uidx = (const int*)d_in[13];
    const int*   midx = (const int*)d_in[14];
    float* out = (float*)d_out;
    u16*   wt  = (u16*)d_ws;

    hipLaunchKernelGGL(prep_weights, dim3(64), dim3(256), 0, stream,
                       w1, w2, sdbw, sscw, auxw, wt);
    hipLaunchKernelGGL(sgn_mfma, dim3(NBLK_M + NBLK_U), dim3(256), 0, stream,
                       x3d, b1, lng, lnb, bb2, sdbb, sscb, auxb,
                       uidx, midx, wt, out);
}